// Round 1
// baseline (6701.048 us; speedup 1.0000x reference)
//
#include <hip/hip_runtime.h>

// Problem constants (from reference)
#define HH 2048
#define WW 2048
#define WSK (HH + WW - 1)   // 4095 skewed columns
#define RPT 8               // rows per thread in scan
#define NT  (HH / RPT)      // 256 threads -> 4 waves, one workgroup
#define FC_IN 1024
#define FC_OUT 10
#define NFLAT ((HH * WW) / FC_IN)   // 4096 flat rows

// Fast tanh: tanh(x) = 1 - 2/(exp2(2*log2(e)*x) + 1)
// exp2 + rcp are single hw transcendentals; error ~1e-7 rel, threshold is 7e-2.
// Saturates correctly for |x| large (exp2 -> inf -> rcp -> 0 -> 1.0).
__device__ __forceinline__ float tanh_fast(float x) {
  float e = __builtin_amdgcn_exp2f(x * 2.88539008177792681472f); // 2/ln(2)
  float r = __builtin_amdgcn_rcpf(e + 1.0f);
  return __builtin_fmaf(-2.0f, r, 1.0f);
}

// Sequential diagonal scan. One workgroup; state h[2048] lives in registers
// (8 rows/thread). Per column: exchange boundary h via double-buffered LDS
// (one barrier), compute 8 tanh, store column to actsT[c][r] (coalesced).
__global__ __launch_bounds__(NT) void scan_kernel(
    const float* __restrict__ img, const float* __restrict__ w_in,
    const float* __restrict__ b_in, const float* __restrict__ w_state,
    const float* __restrict__ b_state, float* __restrict__ actsT) {
  const int t = threadIdx.x;
  const int r0 = t * RPT;
  const float k0 = w_state[0];
  const float k1 = w_state[1];
  const float w  = w_in[0];
  const float C  = b_in[0] + b_state[0];   // constant part of input term

  // xbuf[p][t+1] = new h[last row] of thread t, produced at column c with
  // p=(c+1)&1, consumed by thread t+1 at column c+1. Slot 0 stays 0 (h[-1]=0).
  __shared__ float xbuf[2][NT + 1];

  float h[RPT];
  #pragma unroll
  for (int j = 0; j < RPT; ++j) h[j] = 0.0f;

  xbuf[0][t + 1] = 0.0f;
  if (t == 0) { xbuf[0][0] = 0.0f; xbuf[1][0] = 0.0f; }

  const float* rowp[RPT];
  #pragma unroll
  for (int j = 0; j < RPT; ++j) rowp[j] = img + (size_t)(r0 + j) * WW;

  // Preload column 0 inputs: cur[j] = (in-range ? w*img[r][c-r] : 0) + C
  float cur[RPT];
  #pragma unroll
  for (int j = 0; j < RPT; ++j) {
    int idx = 0 - (r0 + j);
    int cl = idx < 0 ? 0 : (idx > WW - 1 ? WW - 1 : idx);
    float v = rowp[j][cl];
    cur[j] = ((unsigned)idx < (unsigned)WW) ? fmaf(w, v, C) : C;
  }
  __syncthreads();

  for (int c = 0; c < WSK; ++c) {
    float prev = xbuf[c & 1][t];   // old h of row r0-1 (needed only for j=0, computed last)

    // Prefetch next column's inputs (hidden under this column's compute)
    int cn = (c + 1 < WSK) ? c + 1 : WSK - 1;
    float nxt[RPT];
    #pragma unroll
    for (int j = 0; j < RPT; ++j) {
      int idx = cn - (r0 + j);
      int cl = idx < 0 ? 0 : (idx > WW - 1 ? WW - 1 : idx);
      float v = rowp[j][cl];
      nxt[j] = ((unsigned)idx < (unsigned)WW) ? fmaf(w, v, C) : C;
    }

    // Reverse order so h[j-1] read is still the old value (in-place update).
    #pragma unroll
    for (int j = RPT - 1; j >= 1; --j) {
      h[j] = tanh_fast(fmaf(k0, h[j - 1], fmaf(k1, h[j], cur[j])));
    }
    h[0] = tanh_fast(fmaf(k0, prev, fmaf(k1, h[0], cur[0])));

    // Publish boundary for next column, store column (coalesced, 8KB/wavegroup)
    xbuf[(c + 1) & 1][t + 1] = h[RPT - 1];

    float4* dst = (float4*)(actsT + (size_t)c * HH + r0);
    dst[0] = make_float4(h[0], h[1], h[2], h[3]);
    dst[1] = make_float4(h[4], h[5], h[6], h[7]);

    __syncthreads();

    #pragma unroll
    for (int j = 0; j < RPT; ++j) cur[j] = nxt[j];
  }
}

// Unskew + FC fused: flat[i][k] = unskewed[i>>1][(i&1)*1024 + k]
//                              = actsT[(i>>1) + (i&1)*1024 + k][i>>1]
// One wave per flat row; strided dot over k, butterfly-free shfl_down reduce.
__global__ __launch_bounds__(64) void fc_kernel(
    const float* __restrict__ actsT, const float* __restrict__ fc_w,
    const float* __restrict__ fc_b, float* __restrict__ out) {
  const int i = blockIdx.x;
  const int lane = threadIdx.x;
  const int r = i >> 1;
  const int base = (i & 1) << 10;

  float acc[FC_OUT];
  #pragma unroll
  for (int j = 0; j < FC_OUT; ++j) acc[j] = 0.0f;

  for (int k = lane; k < FC_IN; k += 64) {
    float v = actsT[(size_t)(r + base + k) * HH + r];
    #pragma unroll
    for (int j = 0; j < FC_OUT; ++j)
      acc[j] = fmaf(v, fc_w[j * FC_IN + k], acc[j]);
  }

  #pragma unroll
  for (int j = 0; j < FC_OUT; ++j) {
    #pragma unroll
    for (int off = 32; off > 0; off >>= 1)
      acc[j] += __shfl_down(acc[j], off);
  }

  if (lane == 0) {
    #pragma unroll
    for (int j = 0; j < FC_OUT; ++j)
      out[i * FC_OUT + j] = acc[j] + fc_b[j];
  }
}

extern "C" void kernel_launch(void* const* d_in, const int* in_sizes, int n_in,
                              void* d_out, int out_size, void* d_ws, size_t ws_size,
                              hipStream_t stream) {
  const float* x       = (const float*)d_in[0];
  const float* w_in    = (const float*)d_in[1];
  const float* b_in    = (const float*)d_in[2];
  const float* w_state = (const float*)d_in[3];
  const float* b_state = (const float*)d_in[4];
  const float* fc_w    = (const float*)d_in[5];
  const float* fc_b    = (const float*)d_in[6];
  float* out   = (float*)d_out;
  float* actsT = (float*)d_ws;   // needs WSK*HH*4 = 33.5 MB of workspace

  scan_kernel<<<1, NT, 0, stream>>>(x, w_in, b_in, w_state, b_state, actsT);
  fc_kernel<<<NFLAT, 64, 0, stream>>>(actsT, fc_w, fc_b, out);
}

// Round 3
// 4798.650 us; speedup vs baseline: 1.3964x; 1.3964x over previous
//
#include <hip/hip_runtime.h>

// Problem constants (from reference)
#define HH 2048
#define WW 2048
#define WSK (HH + WW - 1)   // 4095 skewed columns
#define NW  8               // waves per block
#define NT  (NW * 64)       // 512 threads
#define RPT (HH / NT)       // 4 rows per thread
#define KCH 32              // columns per chunk (barrier period)
#define NCH ((WSK + KCH - 1) / KCH)   // 128 chunks
#define FC_IN 1024
#define FC_OUT 10
#define NFLAT ((HH * WW) / FC_IN)     // 4096 flat rows

// tanh with the 2/ln2 scale pre-folded into the argument:
// tanh(x) = 1 - 2/(exp2(x*2/ln2) + 1); caller passes xs = x*2/ln2.
__device__ __forceinline__ float tanh_pre(float xs) {
  float e = __builtin_amdgcn_exp2f(xs);
  float r = __builtin_amdgcn_rcpf(e + 1.0f);
  return __builtin_fmaf(-2.0f, r, 1.0f);
}

// Diagonal-wavefront RNN scan, single block, 8 software-pipelined waves.
// Wave w owns rows [w*256, (w+1)*256); at epoch e it processes column chunk
// (e - w). Intra-wave row boundary moves by __shfl_up (lockstep, no sync).
// Inter-wave boundary values flow through a double-buffered LDS ring with ONE
// __syncthreads per 32-column chunk.
//
// Ring semantics (R2 fix): ring[e&1][w][i] holds the boundary value wave w+1
// needs at column c0+i, i.e. wave w's h[last] AFTER column c0+i-1.
//   slot 0     <- written at chunk start (h from end of previous chunk)
//   slot cc+1  <- written after processing column c0+cc (skipped for last col)
__global__ __launch_bounds__(NT) void scan_kernel(
    const float* __restrict__ img, const float* __restrict__ w_in,
    const float* __restrict__ b_in, const float* __restrict__ w_state,
    const float* __restrict__ b_state, float* __restrict__ actsT) {
  const int t = threadIdx.x;
  const int wv = t >> 6;
  const int lane = t & 63;
  const int r0 = t * RPT;   // first global row this thread owns

  const float S = 2.88539008177792681472f;   // 2/ln(2)
  const float k0s = w_state[0] * S;
  const float k1s = w_state[1] * S;
  const float ws  = w_in[0] * S;
  const float Cs  = (b_in[0] + b_state[0]) * S;

  __shared__ float ring[2][NW][KCH];

  float h[RPT];
  #pragma unroll
  for (int j = 0; j < RPT; ++j) h[j] = 0.0f;

  const float* rp[RPT];
  #pragma unroll
  for (int j = 0; j < RPT; ++j) rp[j] = img + (size_t)(r0 + j) * WW;

  for (int e = 0; e < NCH + NW - 1; ++e) {
    const int ch = e - wv;
    if (ch >= 0 && ch < NCH) {
      const int c0 = ch * KCH;
      const int cend = (c0 + KCH < WSK) ? c0 + KCH : WSK;

      // Publish slot 0: boundary the consumer needs at the chunk's first
      // column = our h[last] after the previous chunk's last column.
      if (lane == 63) ring[e & 1][wv][0] = h[RPT - 1];

      // Preload inputs for first column of the chunk.
      float cur[RPT];
      #pragma unroll
      for (int j = 0; j < RPT; ++j) {
        int idx = c0 - (r0 + j);
        int cl = idx < 0 ? 0 : (idx > WW - 1 ? WW - 1 : idx);
        float v = rp[j][cl];
        cur[j] = ((unsigned)idx < (unsigned)WW) ? fmaf(ws, v, Cs) : Cs;
      }

      for (int c = c0; c < cend; ++c) {
        const int cc = c - c0;

        // Boundary value: old h[last row] of the thread above (pre-update).
        float up = __shfl_up(h[RPT - 1], 1);
        float prev;
        if (lane == 0)
          prev = (wv == 0) ? 0.0f : ring[(e & 1) ^ 1][wv - 1][cc];
        else
          prev = up;

        // Prefetch next column's inputs (clamped at chunk end).
        const int cn = (c + 1 < cend) ? c + 1 : cend - 1;
        float nxt[RPT];
        #pragma unroll
        for (int j = 0; j < RPT; ++j) {
          int idx = cn - (r0 + j);
          int cl = idx < 0 ? 0 : (idx > WW - 1 ? WW - 1 : idx);
          float v = rp[j][cl];
          nxt[j] = ((unsigned)idx < (unsigned)WW) ? fmaf(ws, v, Cs) : Cs;
        }

        // Reverse order: h[j-1] must still be the old value.
        #pragma unroll
        for (int j = RPT - 1; j >= 1; --j)
          h[j] = tanh_pre(fmaf(k0s, h[j - 1], fmaf(k1s, h[j], cur[j])));
        h[0] = tanh_pre(fmaf(k0s, prev, fmaf(k1s, h[0], cur[0])));

        // Publish post-column-c boundary into the slot the consumer reads
        // at column c+1. Last column's value is next epoch's slot 0.
        if (lane == 63 && cc + 1 < KCH) ring[e & 1][wv][cc + 1] = h[RPT - 1];

        *(float4*)(actsT + (size_t)c * HH + r0) =
            make_float4(h[0], h[1], h[2], h[3]);

        #pragma unroll
        for (int j = 0; j < RPT; ++j) cur[j] = nxt[j];
      }
    }
    __syncthreads();   // once per 32 columns, not per column
  }
}

// Unskew + FC fused: flat[i][k] = actsT[(i>>1) + (i&1)*1024 + k][i>>1]
// One wave per flat row; strided dot over k, shfl_down reduce.
__global__ __launch_bounds__(64) void fc_kernel(
    const float* __restrict__ actsT, const float* __restrict__ fc_w,
    const float* __restrict__ fc_b, float* __restrict__ out) {
  const int i = blockIdx.x;
  const int lane = threadIdx.x;
  const int r = i >> 1;
  const int base = (i & 1) << 10;

  float acc[FC_OUT];
  #pragma unroll
  for (int j = 0; j < FC_OUT; ++j) acc[j] = 0.0f;

  for (int k = lane; k < FC_IN; k += 64) {
    float v = actsT[(size_t)(r + base + k) * HH + r];
    #pragma unroll
    for (int j = 0; j < FC_OUT; ++j)
      acc[j] = fmaf(v, fc_w[j * FC_IN + k], acc[j]);
  }

  #pragma unroll
  for (int j = 0; j < FC_OUT; ++j) {
    #pragma unroll
    for (int off = 32; off > 0; off >>= 1)
      acc[j] += __shfl_down(acc[j], off);
  }

  if (lane == 0) {
    #pragma unroll
    for (int j = 0; j < FC_OUT; ++j)
      out[i * FC_OUT + j] = acc[j] + fc_b[j];
  }
}

extern "C" void kernel_launch(void* const* d_in, const int* in_sizes, int n_in,
                              void* d_out, int out_size, void* d_ws, size_t ws_size,
                              hipStream_t stream) {
  const float* x       = (const float*)d_in[0];
  const float* w_in    = (const float*)d_in[1];
  const float* b_in    = (const float*)d_in[2];
  const float* w_state = (const float*)d_in[3];
  const float* b_state = (const float*)d_in[4];
  const float* fc_w    = (const float*)d_in[5];
  const float* fc_b    = (const float*)d_in[6];
  float* out   = (float*)d_out;
  float* actsT = (float*)d_ws;   // WSK*HH*4 = 33.5 MB of workspace

  scan_kernel<<<1, NT, 0, stream>>>(x, w_in, b_in, w_state, b_state, actsT);
  fc_kernel<<<NFLAT, 64, 0, stream>>>(actsT, fc_w, fc_b, out);
}

// Round 4
// 970.259 us; speedup vs baseline: 6.9065x; 4.9457x over previous
//
#include <hip/hip_runtime.h>

// Problem constants (from reference)
#define HH 2048
#define WW 2048
#define WSK (HH + WW - 1)   // 4095 real skewed columns
#define WSKP 4096           // padded column count (pad col = pure bias, unused by fc)
#define NW  8               // waves per block (scan)
#define NT  (NW * 64)       // 512 threads
#define RPT (HH / NT)       // 4 rows per thread
#define KCH 64              // columns per chunk (barrier period)
#define NCH (WSKP / KCH)    // 64 chunks, all full
#define PFD 8               // register prefetch depth (columns)
#define FC_IN 1024
#define FC_OUT 10
#define NFLAT ((HH * WW) / FC_IN)   // 4096 flat rows

// tanh with the 2/ln2 scale pre-folded into the argument:
// tanh(x) = 1 - 2/(exp2(x*2/ln2) + 1); caller passes xs = x*2/ln2.
__device__ __forceinline__ float tanh_pre(float xs) {
  float e = __builtin_amdgcn_exp2f(xs);
  float r = __builtin_amdgcn_rcpf(e + 1.0f);
  return __builtin_fmaf(-2.0f, r, 1.0f);
}

// Materialize the pre-scaled skewed input (R2 was L1-request-bound on this
// diagonal gather inside the scan: 2048 distinct cache lines per column
// through ONE CU's L1. Here the gather is spread over all 256 CUs and the
// scan reads back fully coalesced.)
//   inp[c*HH + r] = S*(w*img[r][c-r] + b_in + b_state)   (in-image)
//                 = S*(b_in + b_state)                    (off-image / pad)
__global__ __launch_bounds__(256) void skew_kernel(
    const float* __restrict__ img, const float* __restrict__ w_in,
    const float* __restrict__ b_in, const float* __restrict__ w_state,
    const float* __restrict__ b_state, float* __restrict__ inp) {
  const float S = 2.88539008177792681472f;   // 2/ln(2)
  const float ws = w_in[0] * S;
  const float Cs = (b_in[0] + b_state[0]) * S;
  int gid = blockIdx.x * 256 + threadIdx.x;  // gid = c*HH + r
  int r = gid & (HH - 1);
  int c = gid >> 11;
  int idx = c - r;
  float v = Cs;
  if ((unsigned)idx < (unsigned)WW) v = fmaf(ws, img[(size_t)r * WW + idx], Cs);
  inp[gid] = v;
}

// Diagonal-wavefront RNN scan, single block, 8 software-pipelined waves.
// Wave w owns rows [w*256,(w+1)*256); epoch e -> chunk e-w. In-place:
// reads inp column c+PFD (register prefetch ring) while storing acts over
// column c. Per-wave rows are disjoint, loads precede stores in program
// order, so in-place is race-free.
// Ring semantics (verified R2): ring[e&1][w][i] = wave w's last-row h AFTER
// column c0+i-1 (slot 0 written at chunk start, slot cc+1 after column cc).
__global__ __launch_bounds__(NT) void scan_kernel(
    const float* __restrict__ w_state, float* __restrict__ buf) {
  const int t = threadIdx.x;
  const int wv = t >> 6;
  const int lane = t & 63;
  const int r0 = t * RPT;

  const float S = 2.88539008177792681472f;
  const float k0s = w_state[0] * S;
  const float k1s = w_state[1] * S;

  __shared__ float ring[2][NW][KCH];

  float h0 = 0.f, h1 = 0.f, h2 = 0.f, h3 = 0.f;
  float* colp = buf + r0;

  // Prime the prefetch ring with columns 0..PFD-1 (own rows only — safe).
  float4 pf[PFD];
  #pragma unroll
  for (int d = 0; d < PFD; ++d)
    pf[d] = *(const float4*)(colp + (size_t)d * HH);

  for (int e = 0; e < NCH + NW - 1; ++e) {
    const int ch = e - wv;
    if (0 <= ch && ch < NCH) {
      const int c0 = ch * KCH;
      if (lane == 63) ring[e & 1][wv][0] = h3;
      const float* rring = &ring[(e & 1) ^ 1][wv > 0 ? wv - 1 : 0][0];
      float ringv = rring[0];   // broadcast LDS read (garbage if wv==0, unused)

      #pragma unroll 8
      for (int cc = 0; cc < KCH; ++cc) {
        const int c = c0 + cc;
        const int d = cc & (PFD - 1);   // static per unrolled body (c0%8==0)
        float4 cur = pf[d];

        // Reissue prefetch PFD columns ahead (clamped; redundant at tail).
        int cp = c + PFD; cp = cp < WSKP ? cp : WSKP - 1;
        pf[d] = *(const float4*)(colp + (size_t)cp * HH);

        // Prefetch next column's inter-wave boundary value (broadcast read).
        float ringn = rring[cc + 1 < KCH ? cc + 1 : KCH - 1];

        // Boundary: old h[last row] of the thread above (pre-update).
        float up = __shfl_up(h3, 1);
        float prev = (lane == 0) ? ((wv == 0) ? 0.0f : ringv) : up;

        // All four rows use pre-update values -> independent tanh chains.
        float n3 = tanh_pre(fmaf(k0s, h2, fmaf(k1s, h3, cur.w)));
        float n2 = tanh_pre(fmaf(k0s, h1, fmaf(k1s, h2, cur.z)));
        float n1 = tanh_pre(fmaf(k0s, h0, fmaf(k1s, h1, cur.y)));
        float n0 = tanh_pre(fmaf(k0s, prev, fmaf(k1s, h0, cur.x)));
        h0 = n0; h1 = n1; h2 = n2; h3 = n3;

        // Publish post-column boundary for the consumer's column c+1.
        if (lane == 63 && cc + 1 < KCH) ring[e & 1][wv][cc + 1] = h3;

        // Store acts over inp (in-place), coalesced 1KB per wave.
        *(float4*)(colp + (size_t)c * HH) = make_float4(h0, h1, h2, h3);

        ringv = ringn;
      }
    }
    __syncthreads();   // once per 64 columns
  }
}

// Unskew + FC fused: flat[i][k] = acts[(i>>1) + (i&1)*1024 + k][i>>1]
// One wave per flat row; strided dot over k, shfl_down reduce.
__global__ __launch_bounds__(64) void fc_kernel(
    const float* __restrict__ acts, const float* __restrict__ fc_w,
    const float* __restrict__ fc_b, float* __restrict__ out) {
  const int i = blockIdx.x;
  const int lane = threadIdx.x;
  const int r = i >> 1;
  const int base = (i & 1) << 10;

  float acc[FC_OUT];
  #pragma unroll
  for (int j = 0; j < FC_OUT; ++j) acc[j] = 0.0f;

  for (int k = lane; k < FC_IN; k += 64) {
    float v = acts[(size_t)(r + base + k) * HH + r];
    #pragma unroll
    for (int j = 0; j < FC_OUT; ++j)
      acc[j] = fmaf(v, fc_w[j * FC_IN + k], acc[j]);
  }

  #pragma unroll
  for (int j = 0; j < FC_OUT; ++j) {
    #pragma unroll
    for (int off = 32; off > 0; off >>= 1)
      acc[j] += __shfl_down(acc[j], off);
  }

  if (lane == 0) {
    #pragma unroll
    for (int j = 0; j < FC_OUT; ++j)
      out[i * FC_OUT + j] = acc[j] + fc_b[j];
  }
}

extern "C" void kernel_launch(void* const* d_in, const int* in_sizes, int n_in,
                              void* d_out, int out_size, void* d_ws, size_t ws_size,
                              hipStream_t stream) {
  const float* x       = (const float*)d_in[0];
  const float* w_in    = (const float*)d_in[1];
  const float* b_in    = (const float*)d_in[2];
  const float* w_state = (const float*)d_in[3];
  const float* b_state = (const float*)d_in[4];
  const float* fc_w    = (const float*)d_in[5];
  const float* fc_b    = (const float*)d_in[6];
  float* out = (float*)d_out;
  float* buf = (float*)d_ws;   // WSKP*HH*4 = 33.6 MB: inp, then acts in-place

  skew_kernel<<<(WSKP * HH) / 256, 256, 0, stream>>>(x, w_in, b_in, w_state,
                                                     b_state, buf);
  scan_kernel<<<1, NT, 0, stream>>>(w_state, buf);
  fc_kernel<<<NFLAT, 64, 0, stream>>>(buf, fc_w, fc_b, out);
}

// Round 5
// 853.782 us; speedup vs baseline: 7.8487x; 1.1364x over previous
//
#include <hip/hip_runtime.h>

// Problem constants
#define HH 2048
#define WW 2048
#define WSK 4095            // real skewed columns
#define WSKP 4096           // padded (col 4095 = pad; fc reads cols 0..4094 only)
#define BLKS 8              // pipelined blocks (CUs)
#define NW  4               // waves per block
#define NT  (NW * 64)       // 256 threads, 1 row/thread
#define KCH 32              // columns per chunk (handoff granularity)
#define NCH (WSKP / KCH)    // 128 chunks
#define PFD 16              // register prefetch depth (columns)
#define FC_IN 1024
#define FC_OUT 10
#define NFLAT ((HH * WW) / FC_IN)

// tanh(x) = 1 - 2/(exp2(x*2/ln2)+1); caller passes pre-scaled xs = x*2/ln2.
__device__ __forceinline__ float tanh_pre(float xs) {
  float e = __builtin_amdgcn_exp2f(xs);
  float r = __builtin_amdgcn_rcpf(e + 1.0f);
  return __builtin_fmaf(-2.0f, r, 1.0f);
}

// inp[c*HH+r] = S*(w*img[r][c-r] + b_in + b_state), bias-only off-image.
// Also (re)initializes the flag region (col 4095 rows 1024+) with float-bias
// bits, which can never equal a flag tag (1..NCH) — resets flags each launch.
__global__ __launch_bounds__(256) void skew_kernel(
    const float* __restrict__ img, const float* __restrict__ w_in,
    const float* __restrict__ b_in, const float* __restrict__ b_state,
    float* __restrict__ inp) {
  const float S = 2.88539008177792681472f;   // 2/ln(2)
  const float ws = w_in[0] * S;
  const float Cs = (b_in[0] + b_state[0]) * S;
  int gid = blockIdx.x * 256 + threadIdx.x;  // gid = c*HH + r
  int r = gid & (HH - 1);
  int c = gid >> 11;
  int idx = c - r;
  float v = Cs;
  if ((unsigned)idx < (unsigned)WW) v = fmaf(ws, img[(size_t)r * WW + idx], Cs);
  inp[gid] = v;
}

// 8-block × 4-wave wavefront-pipelined scan, 1 row/thread, in-place on buf.
// Intra-block inter-wave: double-buffered LDS ring (semantics verified R2/R3:
// ring[e&1][w][i] = wave w's h AFTER column c0+i-1; slot 0 at chunk start,
// slot cc+1 after column cc). Inter-block: consumer reads producer's last row
// directly from buf after an acquire-poll on a per-chunk release flag.
__global__ __launch_bounds__(NT) void scan_kernel(
    const float* __restrict__ w_state, float* __restrict__ buf,
    unsigned* __restrict__ flags) {
  const int t = threadIdx.x;
  const int wv = t >> 6;
  const int lane = t & 63;
  const int blk = blockIdx.x;
  const int r = blk * NT + t;                // global row (1 per thread)

  const float S = 2.88539008177792681472f;
  const float k0s = w_state[0] * S;
  const float k1s = w_state[1] * S;

  __shared__ float ring[2][NW][KCH];

  float h = 0.0f;
  float* colp = buf + r;

  // Prime prefetch ring (own row only; written by skew_kernel).
  float pf[PFD];
  #pragma unroll
  for (int d = 0; d < PFD; ++d) pf[d] = colp[(size_t)d * HH];

  const unsigned* upflag = flags + (blk - 1) * NCH;
  unsigned* myflag = flags + blk * NCH;
  const float* uprow = buf + (blk * NT - 1);   // producer's last row (blk>0)

  for (int e = 0; e < NCH + NW - 1; ++e) {
    const int ch = e - wv;
    if (0 <= ch && ch < NCH) {
      const int c0 = ch * KCH;

      // Boundary source for lane 0 of this wave.
      float bval = 0.0f;      // wave 0: per-lane boundary values from above blk
      float ringv = 0.0f;     // waves 1..3: LDS ring value for column c0
      const float* rring = &ring[(e & 1) ^ 1][wv > 0 ? wv - 1 : 0][0];
      if (wv == 0) {
        if (blk > 0) {
          const unsigned want = (unsigned)(ch + 1);
          while (__hip_atomic_load(upflag + ch, __ATOMIC_ACQUIRE,
                                   __HIP_MEMORY_SCOPE_AGENT) != want)
            __builtin_amdgcn_s_sleep(1);
          int cl = c0 + lane - 1;     // lane cc holds boundary for column c0+cc
          if (lane < KCH && cl >= 0) bval = uprow[(size_t)cl * HH];
        }
      } else {
        ringv = rring[0];
      }
      if (lane == 63) ring[e & 1][wv][0] = h;

      #pragma unroll 16
      for (int cc = 0; cc < KCH; ++cc) {
        const int c = c0 + cc;
        const int d = cc & (PFD - 1);
        float cur = pf[d];

        int cp = c + PFD; cp = cp < WSKP - 1 ? cp : WSKP - 1;  // clamp
        pf[d] = colp[(size_t)cp * HH];

        float ringn = (wv > 0) ? rring[cc + 1 < KCH ? cc + 1 : KCH - 1] : 0.0f;

        float up = __shfl_up(h, 1);
        float prev;
        if (wv == 0) {
          float pv = __shfl(bval, cc);     // broadcast slot cc
          prev = lane ? up : pv;           // blk==0: bval==0 -> h[-1]=0
        } else {
          prev = lane ? up : ringv;
        }

        h = tanh_pre(fmaf(k0s, prev, fmaf(k1s, h, cur)));

        if (lane == 63 && cc + 1 < KCH) ring[e & 1][wv][cc + 1] = h;
        if (c != WSKP - 1)                 // never store pad col (flags live there)
          colp[(size_t)c * HH] = h;

        ringv = ringn;
      }

      // Publish chunk to next block: release orders lane 63's prior stores
      // (its row IS the boundary row the consumer reads).
      if (wv == NW - 1 && lane == 63)
        __hip_atomic_store(myflag + ch, (unsigned)(ch + 1), __ATOMIC_RELEASE,
                           __HIP_MEMORY_SCOPE_AGENT);
    }
    __syncthreads();   // rotate LDS ring double-buffer
  }
}

// Unskew + FC fused: flat[i][k] = acts[(i>>1) + (i&1)*1024 + k][i>>1]
__global__ __launch_bounds__(64) void fc_kernel(
    const float* __restrict__ acts, const float* __restrict__ fc_w,
    const float* __restrict__ fc_b, float* __restrict__ out) {
  const int i = blockIdx.x;
  const int lane = threadIdx.x;
  const int r = i >> 1;
  const int base = (i & 1) << 10;

  float acc[FC_OUT];
  #pragma unroll
  for (int j = 0; j < FC_OUT; ++j) acc[j] = 0.0f;

  for (int k = lane; k < FC_IN; k += 64) {
    float v = acts[(size_t)(r + base + k) * HH + r];
    #pragma unroll
    for (int j = 0; j < FC_OUT; ++j)
      acc[j] = fmaf(v, fc_w[j * FC_IN + k], acc[j]);
  }

  #pragma unroll
  for (int j = 0; j < FC_OUT; ++j) {
    #pragma unroll
    for (int off = 32; off > 0; off >>= 1)
      acc[j] += __shfl_down(acc[j], off);
  }

  if (lane == 0) {
    #pragma unroll
    for (int j = 0; j < FC_OUT; ++j)
      out[i * FC_OUT + j] = acc[j] + fc_b[j];
  }
}

extern "C" void kernel_launch(void* const* d_in, const int* in_sizes, int n_in,
                              void* d_out, int out_size, void* d_ws, size_t ws_size,
                              hipStream_t stream) {
  const float* x       = (const float*)d_in[0];
  const float* w_in    = (const float*)d_in[1];
  const float* b_in    = (const float*)d_in[2];
  const float* w_state = (const float*)d_in[3];
  const float* b_state = (const float*)d_in[4];
  const float* fc_w    = (const float*)d_in[5];
  const float* fc_b    = (const float*)d_in[6];
  float* out = (float*)d_out;
  float* buf = (float*)d_ws;   // WSKP*HH*4 = 32 MiB: inp -> acts in-place
  // Flags: pad column 4095, rows 1024..2047 (8*NCH u32 = 4 KB). Never stored
  // by scan, never read by fc; skew re-inits it with float-bias bits (!=1..128).
  unsigned* flags = (unsigned*)(buf + (size_t)(WSKP - 1) * HH + 1024);

  skew_kernel<<<(WSKP * HH) / 256, 256, 0, stream>>>(x, w_in, b_in, b_state, buf);
  scan_kernel<<<BLKS, NT, 0, stream>>>(w_state, buf, flags);
  fc_kernel<<<NFLAT, 64, 0, stream>>>(buf, fc_w, fc_b, out);
}

// Round 6
// 822.220 us; speedup vs baseline: 8.1499x; 1.0384x over previous
//
#include <hip/hip_runtime.h>

// Problem constants
#define HH 2048
#define WW 2048
#define WSK 4095            // real skewed columns
#define WSKP 4096           // padded (col 4095 = pad; fc reads cols 0..4094 only)
#define BLKS 8              // pipelined blocks (CUs)
#define NW  4               // waves per block
#define NT  (NW * 64)       // 256 threads, 1 row/thread
#define KCH 32              // columns per chunk (handoff granularity)
#define NCH (WSKP / KCH)    // 128 chunks
#define PFD 16              // register prefetch depth (columns)
#define FC_IN 1024
#define FC_OUT 10
#define NFLAT ((HH * WW) / FC_IN)

// tanh(x) = 1 - 2/(exp2(x*2/ln2)+1); caller passes pre-scaled xs = x*2/ln2.
__device__ __forceinline__ float tanh_pre(float xs) {
  float e = __builtin_amdgcn_exp2f(xs);
  float r = __builtin_amdgcn_rcpf(e + 1.0f);
  return __builtin_fmaf(-2.0f, r, 1.0f);
}

// Full-wave shift-up-by-1 via DPP wave_shr:1 (gfx9-lineage, ~4-8 cyc vs
// ds_bpermute ~30): result[l] = src[l-1], result[0] = old (bound_ctrl=0
// keeps the 'old' operand in lanes with no source). This puts the boundary
// value into lane 0 with zero extra selects.
__device__ __forceinline__ float wave_shr1(float src, float old) {
  int r = __builtin_amdgcn_update_dpp(
      __builtin_bit_cast(int, old), __builtin_bit_cast(int, src),
      0x138 /*wave_shr:1*/, 0xF, 0xF, false);
  return __builtin_bit_cast(float, r);
}

// inp[c*HH+r] = S*(w*img[r][c-r] + b_in + b_state), bias-only off-image.
// Also re-inits the flag region (col 4095 rows 1024+) with float-bias bits,
// which never equal a flag tag (1..NCH) — resets flags each launch.
__global__ __launch_bounds__(256) void skew_kernel(
    const float* __restrict__ img, const float* __restrict__ w_in,
    const float* __restrict__ b_in, const float* __restrict__ b_state,
    float* __restrict__ inp) {
  const float S = 2.88539008177792681472f;   // 2/ln(2)
  const float ws = w_in[0] * S;
  const float Cs = (b_in[0] + b_state[0]) * S;
  int gid = blockIdx.x * 256 + threadIdx.x;  // gid = c*HH + r
  int r = gid & (HH - 1);
  int c = gid >> 11;
  int idx = c - r;
  float v = Cs;
  if ((unsigned)idx < (unsigned)WW) v = fmaf(ws, img[(size_t)r * WW + idx], Cs);
  inp[gid] = v;
}

// 8-block × 4-wave wavefront-pipelined scan, 1 row/thread.
// inp/acts are the SAME buffer passed through two __restrict__ params: the
// compiler was inserting a per-column s_waitcnt vmcnt(0) between the acts
// store (col c) and the inp prefetch load (col c+PFD) because it couldn't
// prove no-alias (R4: 432 cyc/col measured vs ~60 cyc dep chain). All
// reorderable load/store pairs here are to disjoint columns (frontiers are
// >= 1 chunk apart), so the restrict is operationally safe.
// Ring semantics (verified R2-R4): ring[e&1][w][i] = wave w's h AFTER column
// c0+i-1; slot 0 at chunk start, slot cc+1 after column cc.
__global__ __launch_bounds__(NT) void scan_kernel(
    const float* __restrict__ w_state, const float* __restrict__ inp,
    float* __restrict__ acts, unsigned* __restrict__ flags) {
  const int t = threadIdx.x;
  const int wv = t >> 6;
  const int lane = t & 63;
  const int blk = blockIdx.x;
  const int r = blk * NT + t;                // global row (1 per thread)

  const float S = 2.88539008177792681472f;
  const float k0s = w_state[0] * S;
  const float k1s = w_state[1] * S;

  __shared__ float ring[2][NW][KCH];

  float h = 0.0f;
  const float* colp_in = inp + r;
  float* colp_out = acts + r;

  // Prime prefetch ring (own row only; written by skew_kernel).
  float pf[PFD];
  #pragma unroll
  for (int d = 0; d < PFD; ++d) pf[d] = colp_in[(size_t)d * HH];

  const unsigned* upflag = flags + (blk - 1) * NCH;
  unsigned* myflag = flags + blk * NCH;
  const float* uprow = acts + (blk * NT - 1);  // producer's last row (blk>0)

  for (int e = 0; e < NCH + NW - 1; ++e) {
    const int ch = e - wv;
    if (0 <= ch && ch < NCH) {
      const int c0 = ch * KCH;

      // Boundary source for lane 0 of this wave.
      float bval = 0.0f;      // wave 0: per-lane boundary values from above blk
      float ringv = 0.0f;     // waves 1..3: LDS ring value for column c0
      const float* rring = &ring[(e & 1) ^ 1][wv > 0 ? wv - 1 : 0][0];
      if (wv == 0) {
        if (blk > 0) {
          const unsigned want = (unsigned)(ch + 1);
          while (__hip_atomic_load(upflag + ch, __ATOMIC_ACQUIRE,
                                   __HIP_MEMORY_SCOPE_AGENT) != want)
            __builtin_amdgcn_s_sleep(1);
          int cl = c0 + lane - 1;     // lane cc holds boundary for column c0+cc
          if (lane < KCH && cl >= 0) bval = uprow[(size_t)cl * HH];
        }
      } else {
        ringv = rring[0];
      }
      if (lane == 63) ring[e & 1][wv][0] = h;

      #pragma unroll 16
      for (int cc = 0; cc < KCH; ++cc) {
        const int c = c0 + cc;
        const int d = cc & (PFD - 1);
        float cur = pf[d];

        int cp = c + PFD; cp = cp < WSKP - 1 ? cp : WSKP - 1;  // clamp
        pf[d] = colp_in[(size_t)cp * HH];

        float ringn = (wv > 0) ? rring[cc + 1 < KCH ? cc + 1 : KCH - 1] : 0.0f;

        // Lane-0 boundary value (independent of h -> off the critical chain).
        float pv = (wv == 0) ? __shfl(bval, cc) : ringv;   // blk0 wv0: 0
        // prev[l] = h[l-1] (pre-update), prev[0] = pv. Single DPP op.
        float prev = wave_shr1(h, pv);

        h = tanh_pre(fmaf(k0s, prev, fmaf(k1s, h, cur)));

        if (lane == 63 && cc + 1 < KCH) ring[e & 1][wv][cc + 1] = h;
        if (c != WSKP - 1)               // never store pad col (flags live there)
          colp_out[(size_t)c * HH] = h;

        ringv = ringn;
      }

      // Publish chunk to next block: release orders lane 63's prior stores
      // (its row IS the boundary row the consumer reads).
      if (wv == NW - 1 && lane == 63)
        __hip_atomic_store(myflag + ch, (unsigned)(ch + 1), __ATOMIC_RELEASE,
                           __HIP_MEMORY_SCOPE_AGENT);
    }
    __syncthreads();   // rotate LDS ring double-buffer
  }
}

// Unskew + FC fused: flat[i][k] = acts[(i>>1) + (i&1)*1024 + k][i>>1]
__global__ __launch_bounds__(64) void fc_kernel(
    const float* __restrict__ acts, const float* __restrict__ fc_w,
    const float* __restrict__ fc_b, float* __restrict__ out) {
  const int i = blockIdx.x;
  const int lane = threadIdx.x;
  const int r = i >> 1;
  const int base = (i & 1) << 10;

  float acc[FC_OUT];
  #pragma unroll
  for (int j = 0; j < FC_OUT; ++j) acc[j] = 0.0f;

  for (int k = lane; k < FC_IN; k += 64) {
    float v = acts[(size_t)(r + base + k) * HH + r];
    #pragma unroll
    for (int j = 0; j < FC_OUT; ++j)
      acc[j] = fmaf(v, fc_w[j * FC_IN + k], acc[j]);
  }

  #pragma unroll
  for (int j = 0; j < FC_OUT; ++j) {
    #pragma unroll
    for (int off = 32; off > 0; off >>= 1)
      acc[j] += __shfl_down(acc[j], off);
  }

  if (lane == 0) {
    #pragma unroll
    for (int j = 0; j < FC_OUT; ++j)
      out[i * FC_OUT + j] = acc[j] + fc_b[j];
  }
}

extern "C" void kernel_launch(void* const* d_in, const int* in_sizes, int n_in,
                              void* d_out, int out_size, void* d_ws, size_t ws_size,
                              hipStream_t stream) {
  const float* x       = (const float*)d_in[0];
  const float* w_in    = (const float*)d_in[1];
  const float* b_in    = (const float*)d_in[2];
  const float* w_state = (const float*)d_in[3];
  const float* b_state = (const float*)d_in[4];
  const float* fc_w    = (const float*)d_in[5];
  const float* fc_b    = (const float*)d_in[6];
  float* out = (float*)d_out;
  float* buf = (float*)d_ws;   // WSKP*HH*4 = 32 MiB: inp -> acts in-place
  // Flags: pad column 4095, rows 1024..2047. Never stored by scan, never read
  // by fc; skew re-inits it with float-bias bits (!= tags 1..128).
  unsigned* flags = (unsigned*)(buf + (size_t)(WSKP - 1) * HH + 1024);

  skew_kernel<<<(WSKP * HH) / 256, 256, 0, stream>>>(x, w_in, b_in, b_state, buf);
  scan_kernel<<<BLKS, NT, 0, stream>>>(w_state, buf, buf, flags);
  fc_kernel<<<NFLAT, 64, 0, stream>>>(buf, fc_w, fc_b, out);
}

// Round 7
// 554.219 us; speedup vs baseline: 12.0910x; 1.4836x over previous
//
#include <hip/hip_runtime.h>

// Problem constants
#define HH 2048
#define WW 2048
#define WSK 4095            // real skewed columns
#define WSKP 4096           // padded (col 4095 = dump column; fc reads 0..4094)
#define BLKS 8              // pipelined blocks (CUs)
#define NW  4               // waves per block
#define NT  (NW * 64)       // 256 threads, 1 row/thread
#define KCH 32              // columns per chunk = prefetch depth = unroll
#define NCH (WSKP / KCH)    // 128 chunks
#define FC_IN 1024
#define FC_OUT 10
#define NFLAT ((HH * WW) / FC_IN)

// tanh(x) = 1 - 2/(exp2(x*2/ln2)+1); caller passes pre-scaled xs = x*2/ln2.
__device__ __forceinline__ float tanh_pre(float xs) {
  float e = __builtin_amdgcn_exp2f(xs);
  float r = __builtin_amdgcn_rcpf(e + 1.0f);
  return __builtin_fmaf(-2.0f, r, 1.0f);
}

// Full-wave shift-up-by-1 via DPP wave_shr:1 (verified R5: exact absmax).
// result[l] = src[l-1], result[0] = old.
__device__ __forceinline__ float wave_shr1(float src, float old) {
  int r = __builtin_amdgcn_update_dpp(
      __builtin_bit_cast(int, old), __builtin_bit_cast(int, src),
      0x138 /*wave_shr:1*/, 0xF, 0xF, false);
  return __builtin_bit_cast(float, r);
}

// inp[c*HH+r] = S*(w*img[r][c-r] + b_in + b_state), bias-only off-image.
__global__ __launch_bounds__(256) void skew_kernel(
    const float* __restrict__ img, const float* __restrict__ w_in,
    const float* __restrict__ b_in, const float* __restrict__ b_state,
    float* __restrict__ inp) {
  const float S = 2.88539008177792681472f;   // 2/ln(2)
  const float ws = w_in[0] * S;
  const float Cs = (b_in[0] + b_state[0]) * S;
  int gid = blockIdx.x * 256 + threadIdx.x;  // gid = c*HH + r
  int r = gid & (HH - 1);
  int c = gid >> 11;
  int idx = c - r;
  float v = Cs;
  if ((unsigned)idx < (unsigned)WW) v = fmaf(ws, img[(size_t)r * WW + idx], Cs);
  inp[gid] = v;
}

// 8-block × 4-wave wavefront-pipelined scan, 1 row/thread.
// R6 changes vs R5 (703 µs, ~340 cyc/col — waitcnt-conservatism bound):
//  * column loop is 100% branchless (unconditional store; col 4095 is a dump
//    column, flags moved to d_out) -> compiler can emit precise vmcnt waits.
//  * inter-wave ring read batched: ONE ds_read per epoch into lanes, then
//    per-column v_readlane (SALU) -> no per-column LDS latency.
//  * epoch barrier = raw s_barrier + lgkmcnt(0) only (inline asm): the 32
//    next-chunk prefetch loads stay in flight across the epoch boundary
//    (__syncthreads would vmcnt(0)-drain them).
// Ring semantics (verified R2-R5): ring[e&1][w][i] = wave w's h AFTER column
// c0+i-1; slot 0 at chunk start, slot i+1 after column i.
// inp/acts are the same buffer; within a wave, loads touch chunk ch+1 and
// stores chunk ch (same rows, disjoint columns) except the never-consumed
// clamped reload at the final chunk -> restrict is operationally safe.
__global__ __launch_bounds__(NT) void scan_kernel(
    const float* __restrict__ w_state, const float* __restrict__ inp,
    float* __restrict__ acts, unsigned* __restrict__ flags) {
  const int t = threadIdx.x;
  const int wv = t >> 6;
  const int lane = t & 63;
  const int blk = blockIdx.x;
  const int r = blk * NT + t;                // global row (1 per thread)

  const float S = 2.88539008177792681472f;
  const float k0s = w_state[0] * S;
  const float k1s = w_state[1] * S;

  __shared__ float ring[2][NW][KCH];

  float h = 0.0f;
  const float* colp_in = inp + r;
  float* colp_out = acts + r;

  // Prime prefetch registers with chunk 0 (whole chunk).
  float pf[KCH];
  #pragma unroll
  for (int d = 0; d < KCH; ++d) pf[d] = colp_in[(size_t)d * HH];

  const unsigned* upflag = flags + (blk - 1) * NCH;
  unsigned* myflag = flags + blk * NCH;
  const float* uprow = acts + (blk * NT - 1);  // producer's last row (blk>0)

  for (int e = 0; e < NCH + NW - 1; ++e) {
    const int ch = e - wv;
    if (0 <= ch && ch < NCH) {
      const int c0 = ch * KCH;

      // Gather this chunk's 32 boundary values into lanes 0..31 of bvec:
      // lane i = neighbor-row h AFTER column c0+i-1.
      float bvec;
      if (wv == 0) {
        bvec = 0.0f;
        if (blk > 0) {
          const unsigned want = (unsigned)(ch + 1);
          while (__hip_atomic_load(upflag + ch, __ATOMIC_ACQUIRE,
                                   __HIP_MEMORY_SCOPE_AGENT) != want)
            __builtin_amdgcn_s_sleep(1);
          int cl = c0 + lane - 1;
          if (lane < KCH && cl >= 0) bvec = uprow[(size_t)cl * HH];
        }
      } else {
        // Written entirely by wave wv-1 during the previous epoch.
        bvec = ring[(e & 1) ^ 1][wv - 1][lane & (KCH - 1)];
      }
      if (lane == 63) ring[e & 1][wv][0] = h;

      // Next-chunk prefetch base (clamped reload at final chunk, unused).
      const int cb = (ch + 1 < NCH ? ch + 1 : ch) * KCH;

      #pragma unroll
      for (int cc = 0; cc < KCH; ++cc) {
        float cur = pf[cc];
        pf[cc] = colp_in[(size_t)(cb + cc) * HH];

        // Boundary value for lane 0, off the critical chain (SALU readlane).
        float pv = __builtin_bit_cast(float,
            __builtin_amdgcn_readlane(__builtin_bit_cast(int, bvec), cc));
        float prev = wave_shr1(h, pv);   // prev[l]=h[l-1], prev[0]=pv

        h = tanh_pre(fmaf(k0s, prev, fmaf(k1s, h, cur)));

        if (lane == 63 && cc + 1 < KCH) ring[e & 1][wv][cc + 1] = h;
        colp_out[(size_t)(c0 + cc) * HH] = h;   // unconditional (4095 = dump)
      }

      // Publish chunk to next block (release orders lane 63's prior stores;
      // its row IS the boundary row the consumer reads).
      if (wv == NW - 1 && lane == 63)
        __hip_atomic_store(myflag + ch, (unsigned)(ch + 1), __ATOMIC_RELEASE,
                           __HIP_MEMORY_SCOPE_AGENT);
    }
    // LDS-only barrier: rotates the ring double-buffer WITHOUT draining
    // vmcnt, so next-chunk prefetches survive the epoch boundary.
    asm volatile("s_waitcnt lgkmcnt(0)\n\ts_barrier" ::: "memory");
  }
}

// Unskew + FC fused: flat[i][k] = acts[(i>>1) + (i&1)*1024 + k][i>>1]
__global__ __launch_bounds__(64) void fc_kernel(
    const float* __restrict__ acts, const float* __restrict__ fc_w,
    const float* __restrict__ fc_b, float* __restrict__ out) {
  const int i = blockIdx.x;
  const int lane = threadIdx.x;
  const int r = i >> 1;
  const int base = (i & 1) << 10;

  float acc[FC_OUT];
  #pragma unroll
  for (int j = 0; j < FC_OUT; ++j) acc[j] = 0.0f;

  for (int k = lane; k < FC_IN; k += 64) {
    float v = acts[(size_t)(r + base + k) * HH + r];
    #pragma unroll
    for (int j = 0; j < FC_OUT; ++j)
      acc[j] = fmaf(v, fc_w[j * FC_IN + k], acc[j]);
  }

  #pragma unroll
  for (int j = 0; j < FC_OUT; ++j) {
    #pragma unroll
    for (int off = 32; off > 0; off >>= 1)
      acc[j] += __shfl_down(acc[j], off);
  }

  if (lane == 0) {
    #pragma unroll
    for (int j = 0; j < FC_OUT; ++j)
      out[i * FC_OUT + j] = acc[j] + fc_b[j];
  }
}

extern "C" void kernel_launch(void* const* d_in, const int* in_sizes, int n_in,
                              void* d_out, int out_size, void* d_ws, size_t ws_size,
                              hipStream_t stream) {
  const float* x       = (const float*)d_in[0];
  const float* w_in    = (const float*)d_in[1];
  const float* b_in    = (const float*)d_in[2];
  const float* w_state = (const float*)d_in[3];
  const float* b_state = (const float*)d_in[4];
  const float* fc_w    = (const float*)d_in[5];
  const float* fc_b    = (const float*)d_in[6];
  float* out = (float*)d_out;
  float* buf = (float*)d_ws;   // WSKP*HH*4 = 32 MiB: inp -> acts in-place

  // Flags live in d_out (4 KB of its 160 KB): scan writes tags 1..128 there,
  // fc_kernel later overwrites EVERY d_out element with real outputs, so
  // validation is unaffected. Harness poison (0xAA) / memset(0) never equals
  // a tag, so flags are correctly reset before every launch.
  unsigned* flags = (unsigned*)d_out;

  skew_kernel<<<(WSKP * HH) / 256, 256, 0, stream>>>(x, w_in, b_in, b_state, buf);
  scan_kernel<<<BLKS, NT, 0, stream>>>(w_state, buf, buf, flags);
  fc_kernel<<<NFLAT, 64, 0, stream>>>(buf, fc_w, fc_b, out);
}